// Round 3
// baseline (144.023 us; speedup 1.0000x reference)
//
#include <hip/hip_runtime.h>

#define HH 64
#define WW 64
#define CC 128
#define FF 256
#define NTAP 9
#define KD 1152   // NTAP*CC
#define WT_BLOCKS 144                     // 36864 threads, 8 k each

typedef __attribute__((ext_vector_type(8))) short bf16x8;
typedef __attribute__((ext_vector_type(4))) float floatx4;

__device__ inline unsigned short f2bf(float v) {
  union { float f; unsigned u; } c; c.f = v;
  unsigned r = (c.u + 0x7FFFu + ((c.u >> 16) & 1u)) >> 16;  // RNE
  return (unsigned short)r;
}
// HW RNE pack: bf16(lo) | bf16(hi)<<16
__device__ inline unsigned cvt_pk_bf16(float lo, float hi) {
  unsigned r;
  asm("v_cvt_pk_bf16_f32 %0, %1, %2" : "=v"(r) : "v"(lo), "v"(hi));
  return r;
}
__device__ inline float lerp1(float v00, float v10, float v01, float v11, float fy, float fx) {
  float t = v00 + (v10 - v00) * fy;
  float bm = v01 + (v11 - v01) * fy;
  return t + (bm - t) * fx;
}
__device__ inline unsigned lerp_pk(float A00, float A10, float A01, float A11,
                                   float B00, float B10, float B01, float B11,
                                   float fy, float fx) {
  return cvt_pk_bf16(lerp1(A00, A10, A01, A11, fy, fx),
                     lerp1(B00, B10, B01, B11, fy, fx));
}

// Tap offsets packed 2 bits each (meshgrid-faithful order):
// c_iy = {0,0,1,2,2,1,0,2,1} -> 0x18690 ; c_ix = {0,1,1,2,0,2,1,0,2} -> 0x21894
#define IY_PACK 0x18690
#define IX_PACK 0x21894

struct ITap { int b00, b10, b01, b11; float fy, fx; };

__device__ inline ITap tap_setup(const float* __restrict__ offp, int i, int p, int n) {
  const float2 o2 = *(const float2*)(offp + 2 * n);
  float cy = (float)(i - 1 + ((IY_PACK >> (2 * n)) & 3)) + o2.x;
  float cx = (float)(p - 1 + ((IX_PACK >> (2 * n)) & 3)) + o2.y;
  cy = fminf(fmaxf(cy, 0.f), 63.f);
  cx = fminf(fmaxf(cx, 0.f), 63.f);
  const float fy0 = floorf(cy), fx0 = floorf(cx);
  const int y0 = (int)fy0, y1 = (int)ceilf(cy);
  const int x0 = (int)fx0, x1 = (int)ceilf(cx);
  ITap t;
  t.b00 = (y0 * WW + x0) * CC;
  t.b10 = (y1 * WW + x0) * CC;
  t.b01 = (y0 * WW + x1) * CC;
  t.b11 = (y1 * WW + x1) * CC;
  t.fy = cy - fy0;
  t.fx = cx - fx0;
  return t;
}

// ---- Prep: W [k][f] -> Wt [f][k] bf16 only (X stays f32, gathered directly)
__global__ void prep_kernel(const float* __restrict__ W, unsigned short* __restrict__ Wt) {
  const int t = blockIdx.x * 256 + threadIdx.x;  // 0..36863
  const int f = t & 255;
  const int k0 = (t >> 8) * 8;
  unsigned short o[8];
#pragma unroll
  for (int i2 = 0; i2 < 8; ++i2)
    o[i2] = f2bf(W[(size_t)(k0 + i2) * FF + f]);
  *(uint4*)(Wt + (size_t)f * KD + k0) = *(uint4*)o;
}

// f32 bilinear of one tap -> bf16 into swizzled smA. Thread: pos p, chunks c0 & c0+8.
__device__ inline void interp_tap(const float* __restrict__ xb, const float* __restrict__ offp,
                                  int i, int p, int c0, int n, unsigned short* smA) {
  ITap t = tap_setup(offp, i, p, n);
#pragma unroll
  for (int cc = 0; cc < 2; ++cc) {
    const int c  = c0 + cc * 8;
    const int ch = c * 8;
    const float* g00 = xb + t.b00 + ch;
    const float* g10 = xb + t.b10 + ch;
    const float* g01 = xb + t.b01 + ch;
    const float* g11 = xb + t.b11 + ch;
    float4 a00 = *(const float4*)g00, e00 = *(const float4*)(g00 + 4);
    float4 a10 = *(const float4*)g10, e10 = *(const float4*)(g10 + 4);
    float4 a01 = *(const float4*)g01, e01 = *(const float4*)(g01 + 4);
    float4 a11 = *(const float4*)g11, e11 = *(const float4*)(g11 + 4);
    unsigned w0 = lerp_pk(a00.x, a10.x, a01.x, a11.x, a00.y, a10.y, a01.y, a11.y, t.fy, t.fx);
    unsigned w1 = lerp_pk(a00.z, a10.z, a01.z, a11.z, a00.w, a10.w, a01.w, a11.w, t.fy, t.fx);
    unsigned w2 = lerp_pk(e00.x, e10.x, e01.x, e11.x, e00.y, e10.y, e01.y, e11.y, t.fy, t.fx);
    unsigned w3 = lerp_pk(e00.z, e10.z, e01.z, e11.z, e00.w, e10.w, e01.w, e11.w, t.fy, t.fx);
    *(uint4*)&smA[p * 128 + ((c ^ (p & 15)) << 3)] = make_uint4(w0, w1, w2, w3);
  }
}

// ---- Fused interp+GEMM: block = one image row = 64 M x 256 F, K = 1152.
// BK=128 (one full 3x3 tap per kt, 9 kt). 8 waves: kg = wave>>2 splits K in half,
// fg = wave&3 splits F; each wave computes 64M x 64F over its 64-k half (acc[4][4]);
// halves combined via LDS exchange in the epilogue.
// LDS: smA 16KB + smB 64KB = 80KB -> exactly 2 blocks/CU (160 KiB), 16 waves/CU.
__global__ __launch_bounds__(512, 4) void fused_kernel(
    const float* __restrict__ X, const float* __restrict__ Off,
    const unsigned short* __restrict__ Wt, const float* __restrict__ bias,
    float* __restrict__ Out)
{
  __shared__ unsigned short smA[64 * 128];     // 16 KB : 64 pos x 128 k (swizzled 16B chunks)
  __shared__ unsigned short smB[256 * 128];    // 64 KB : 256 F x 128 k (swizzled 16B chunks)

  const int blk = blockIdx.x;       // 0..511
  const int b   = blk & 7;          // batch -> XCD locality (X slice 2MB, L2-resident)
  const int i   = blk >> 3;         // image row y; positions x = 0..63
  const int m0  = (b * 64 + i) * 64;
  const int tid = threadIdx.x;
  const int wave = tid >> 6, lane = tid & 63;
  const int kg = wave >> 2;         // K-half of each tap
  const int fg = wave & 3;          // F quarter (64 F)
  const int arow = lane & 15, aq = lane >> 4;
  const int p  = tid >> 3;          // interp: position 0..63
  const int c0 = tid & 7;           // interp: chunks c0 and c0+8

  const float* xb = X + (size_t)b * (HH * WW * CC);
  const float* offp = Off + ((size_t)(b * HH + i) * WW + p) * (2 * NTAP);

  floatx4 acc[4][4];
#pragma unroll
  for (int mt = 0; mt < 4; ++mt)
#pragma unroll
    for (int ft = 0; ft < 4; ++ft)
      acc[mt][ft] = (floatx4){0.f, 0.f, 0.f, 0.f};

  // B staging: dest shorts offset = pass*4096 + tid*8 -> wave-uniform base + lane*16B (linear).
  // Swizzle applied on the global source (inverse of read-side XOR).
#define STAGE_B(KT)                                                                  \
  {                                                                                  \
    _Pragma("unroll")                                                                \
    for (int pass = 0; pass < 8; ++pass) {                                           \
      const int row = pass * 32 + (tid >> 4);                                        \
      const int kc  = tid & 15;                                                      \
      const unsigned short* gp =                                                     \
          Wt + (size_t)row * KD + (KT) * 128 + ((kc ^ (row & 15)) << 3);             \
      unsigned short* l = (unsigned short*)&smB[row * 128 + kc * 8];                 \
      __builtin_amdgcn_global_load_lds(                                              \
          (const __attribute__((address_space(1))) unsigned int*)gp,                 \
          (__attribute__((address_space(3))) unsigned int*)l, 16, 0, 0);             \
    }                                                                                \
  }

  // ---- prologue: tap 0 interp + B tile 0
  STAGE_B(0)
  interp_tap(xb, offp, i, p, c0, 0, smA);
  __syncthreads();

  for (int kt = 0; kt < 9; ++kt) {
    // ---- MFMA phase: wave's K-half of this tap (all LDS reads precede barrier)
#pragma unroll
    for (int ks = 0; ks < 2; ++ks) {
      bf16x8 afr[4], bfr[4];
      const int slot = (((kg * 8 + ks * 4 + aq) ^ arow) << 3);  // row&15 == arow for A and B
#pragma unroll
      for (int mt = 0; mt < 4; ++mt)
        afr[mt] = *(const bf16x8*)&smA[(mt * 16 + arow) * 128 + slot];
#pragma unroll
      for (int ft = 0; ft < 4; ++ft)
        bfr[ft] = *(const bf16x8*)&smB[(fg * 64 + ft * 16 + arow) * 128 + slot];
#pragma unroll
      for (int mt = 0; mt < 4; ++mt)
#pragma unroll
        for (int ft = 0; ft < 4; ++ft)
          acc[mt][ft] = __builtin_amdgcn_mfma_f32_16x16x32_bf16(
              afr[mt], bfr[ft], acc[mt][ft], 0, 0, 0);
    }
    __syncthreads();   // all reads done -> buffers free for overwrite

    if (kt < 8) {
      STAGE_B(kt + 1)                              // B-DMA issues first (in-order vmcnt)
      interp_tap(xb, offp, i, p, c0, kt + 1, smA); // gathers+lerp hide DMA latency
      __syncthreads();  // drains vmcnt (B-DMA) + lgkm (smA writes)
    }
  }
#undef STAGE_B

  // ---- epilogue: combine K-halves via swizzled LDS exchange (reuse smB = 64KB)
  float* ex = (float*)smB;
  if (kg == 1) {
#pragma unroll
    for (int mt = 0; mt < 4; ++mt)
#pragma unroll
      for (int ft = 0; ft < 4; ++ft) {
        const int f  = fg * 64 + ft * 16 + arow;
        const int cm = mt * 4 + aq;
        *(floatx4*)&ex[f * 64 + ((cm ^ arow) << 2)] = acc[mt][ft];
      }
  }
  __syncthreads();
  if (kg == 0) {
    float bv[4];
#pragma unroll
    for (int ft = 0; ft < 4; ++ft)
      bv[ft] = bias[fg * 64 + ft * 16 + arow];
#pragma unroll
    for (int mt = 0; mt < 4; ++mt) {
#pragma unroll
      for (int ft = 0; ft < 4; ++ft) {
        const int f  = fg * 64 + ft * 16 + arow;
        const int cm = mt * 4 + aq;
        floatx4 o = *(const floatx4*)&ex[f * 64 + ((cm ^ arow) << 2)];
#pragma unroll
        for (int r = 0; r < 4; ++r) {
          const int m = m0 + mt * 16 + aq * 4 + r;
          Out[(size_t)m * FF + f] = acc[mt][ft][r] + o[r] + bv[ft];
        }
      }
    }
  }
}

extern "C" void kernel_launch(void* const* d_in, const int* in_sizes, int n_in,
                              void* d_out, int out_size, void* d_ws, size_t ws_size,
                              hipStream_t stream) {
  const float* X    = (const float*)d_in[0];
  const float* Off  = (const float*)d_in[1];
  const float* W    = (const float*)d_in[2];
  const float* bias = (const float*)d_in[3];
  float* Out = (float*)d_out;

  unsigned short* Wt = (unsigned short*)d_ws;   // 294912 shorts (576 KB)

  prep_kernel<<<WT_BLOCKS, 256, 0, stream>>>(W, Wt);
  fused_kernel<<<512, 512, 0, stream>>>(X, Off, Wt, bias, Out);
}

// Round 4
// 121.379 us; speedup vs baseline: 1.1866x; 1.1866x over previous
//
#include <hip/hip_runtime.h>

#define HH 64
#define WW 64
#define CC 128
#define FF 256
#define NTAP 9
#define KD 1152   // NTAP*CC
#define XELEMS (8 * HH * WW * CC)         // 4194304
#define XCVT_BLOCKS (XELEMS / (256 * 8))  // 2048
#define WT_BLOCKS 144                     // 36864 threads, 8 k each

typedef __attribute__((ext_vector_type(8))) short bf16x8;
typedef __attribute__((ext_vector_type(4))) float floatx4;

__device__ inline unsigned short f2bf(float v) {
  union { float f; unsigned u; } c; c.f = v;
  unsigned r = (c.u + 0x7FFFu + ((c.u >> 16) & 1u)) >> 16;  // RNE
  return (unsigned short)r;
}
__device__ inline float bflo(unsigned u) {
  union { unsigned u; float f; } c; c.u = u << 16; return c.f;
}
__device__ inline float bfhi(unsigned u) {
  union { unsigned u; float f; } c; c.u = u & 0xFFFF0000u; return c.f;
}
// HW RNE pack: bf16(lo) | bf16(hi)<<16 — same rounding as f2bf for finite inputs.
__device__ inline unsigned cvt_pk_bf16(float lo, float hi) {
  unsigned r;
  asm("v_cvt_pk_bf16_f32 %0, %1, %2" : "=v"(r) : "v"(lo), "v"(hi));
  return r;
}

// Bilinear lerp of one 32-bit word (2 bf16 channels). Verified path (rounds 0-2).
__device__ inline unsigned lerp_word(unsigned u00, unsigned u10, unsigned u01, unsigned u11,
                                     float fy, float fx) {
  float v00 = bflo(u00), v10 = bflo(u10), v01 = bflo(u01), v11 = bflo(u11);
  float tx = v00 + (v10 - v00) * fy;
  float tb = v01 + (v11 - v01) * fy;
  float rlo = tx + (tb - tx) * fx;
  v00 = bfhi(u00); v10 = bfhi(u10); v01 = bfhi(u01); v11 = bfhi(u11);
  tx = v00 + (v10 - v00) * fy;
  tb = v01 + (v11 - v01) * fy;
  float rhi = tx + (tb - tx) * fx;
  return cvt_pk_bf16(rlo, rhi);
}

// Tap offsets packed 2 bits each (meshgrid-faithful order):
// c_iy = {0,0,1,2,2,1,0,2,1} -> 0x18690 ; c_ix = {0,1,1,2,0,2,1,0,2} -> 0x21894
#define IY_PACK 0x18690
#define IX_PACK 0x21894

struct ITap { int b00, b10, b01, b11; float fy, fx; };

__device__ inline ITap tap_setup(const float* __restrict__ offp, int i, int p, int n) {
  const float2 o2 = *(const float2*)(offp + 2 * n);
  float cy = (float)(i - 1 + ((IY_PACK >> (2 * n)) & 3)) + o2.x;
  float cx = (float)(p - 1 + ((IX_PACK >> (2 * n)) & 3)) + o2.y;
  cy = fminf(fmaxf(cy, 0.f), 63.f);
  cx = fminf(fmaxf(cx, 0.f), 63.f);
  const float fy0 = floorf(cy), fx0 = floorf(cx);
  const int y0 = (int)fy0, y1 = (int)ceilf(cy);
  const int x0 = (int)fx0, x1 = (int)ceilf(cx);
  ITap t;
  t.b00 = (y0 * WW + x0) * CC;
  t.b10 = (y1 * WW + x0) * CC;
  t.b01 = (y0 * WW + x1) * CC;
  t.b11 = (y1 * WW + x1) * CC;
  t.fy = cy - fy0;
  t.fx = cx - fx0;
  return t;
}

// ---- Prep: X fp32->bf16, and W [k][f] -> Wt [f][k] bf16 (verified in rounds 0-2)
__global__ void prep_kernel(const float* __restrict__ X, const float* __restrict__ W,
                            unsigned short* __restrict__ Xb, unsigned short* __restrict__ Wt) {
  const int blk = blockIdx.x;
  if (blk < XCVT_BLOCKS) {                  // X convert, 8 elems/thread
    const int t = blk * 256 + threadIdx.x;
    const float4* src = (const float4*)(X + (size_t)t * 8);
    float4 a = src[0], b2 = src[1];
    bf16x8 o;
    o[0] = (short)f2bf(a.x);  o[1] = (short)f2bf(a.y);
    o[2] = (short)f2bf(a.z);  o[3] = (short)f2bf(a.w);
    o[4] = (short)f2bf(b2.x); o[5] = (short)f2bf(b2.y);
    o[6] = (short)f2bf(b2.z); o[7] = (short)f2bf(b2.w);
    *(bf16x8*)(Xb + (size_t)t * 8) = o;
  } else {                                  // W transpose: thread = (f, 8 k's)
    const int t = (blk - XCVT_BLOCKS) * 256 + threadIdx.x;  // 0..36863
    const int f = t & 255;
    const int k0 = (t >> 8) * 8;
    unsigned short o[8];
#pragma unroll
    for (int i2 = 0; i2 < 8; ++i2)
      o[i2] = f2bf(W[(size_t)(k0 + i2) * FF + f]);
    *(uint4*)(Wt + (size_t)f * KD + k0) = *(uint4*)o;
  }
}

// bf16 bilinear of one full tap (128 ch) -> swizzled smA. Thread: pos p, chunks c0 & c0+8.
// Each corner read = 8 lanes x 16B = 128B contiguous (L2-friendly).
__device__ inline void interp_tap(const unsigned short* __restrict__ xb,
                                  const float* __restrict__ offp,
                                  int i, int p, int c0, int n, unsigned short* smA) {
  ITap t = tap_setup(offp, i, p, n);
#pragma unroll
  for (int cc = 0; cc < 2; ++cc) {
    const int c  = c0 + cc * 8;
    const int ch = c * 8;
    uint4 q00 = *(const uint4*)(xb + t.b00 + ch);
    uint4 q10 = *(const uint4*)(xb + t.b10 + ch);
    uint4 q01 = *(const uint4*)(xb + t.b01 + ch);
    uint4 q11 = *(const uint4*)(xb + t.b11 + ch);
    unsigned w0 = lerp_word(q00.x, q10.x, q01.x, q11.x, t.fy, t.fx);
    unsigned w1 = lerp_word(q00.y, q10.y, q01.y, q11.y, t.fy, t.fx);
    unsigned w2 = lerp_word(q00.z, q10.z, q01.z, q11.z, t.fy, t.fx);
    unsigned w3 = lerp_word(q00.w, q10.w, q01.w, q11.w, t.fy, t.fx);
    *(uint4*)&smA[p * 128 + ((c ^ (p & 15)) << 3)] = make_uint4(w0, w1, w2, w3);
  }
}

// ---- Fused interp+GEMM: block = one image row = 64 M x 256 F, K = 1152.
// BK=128 (one full 3x3 tap per kt, 9 kt). 8 waves: kg = wave>>2 splits K in half,
// fg = wave&3 splits F; each wave computes 64M x 64F over its 64-k half (acc[4][4]);
// halves combined via LDS exchange in the epilogue.
// LDS: smA 16KB + smB 64KB = 80KB -> 2 blocks/CU, 16 waves/CU.
__global__ __launch_bounds__(512, 4) void fused_kernel(
    const unsigned short* __restrict__ Xb, const float* __restrict__ Off,
    const unsigned short* __restrict__ Wt, const float* __restrict__ bias,
    float* __restrict__ Out)
{
  __shared__ unsigned short smA[64 * 128];     // 16 KB : 64 pos x 128 k (swizzled 16B chunks)
  __shared__ unsigned short smB[256 * 128];    // 64 KB : 256 F x 128 k (swizzled 16B chunks)

  const int blk = blockIdx.x;       // 0..511
  const int b   = blk & 7;          // batch == XCD -> Xb slice (1 MB) L2-resident
  const int i   = blk >> 3;         // image row y; positions x = 0..63
  const int m0  = (b * 64 + i) * 64;
  const int tid = threadIdx.x;
  const int wave = tid >> 6, lane = tid & 63;
  const int kg = wave >> 2;         // K-half of each tap
  const int fg = wave & 3;          // F quarter (64 F)
  const int arow = lane & 15, aq = lane >> 4;
  const int p  = tid >> 3;          // interp: position 0..63
  const int c0 = tid & 7;           // interp: chunks c0 and c0+8

  const unsigned short* xb = Xb + (size_t)b * (HH * WW * CC);
  const float* offp = Off + ((size_t)(b * HH + i) * WW + p) * (2 * NTAP);

  floatx4 acc[4][4];
#pragma unroll
  for (int mt = 0; mt < 4; ++mt)
#pragma unroll
    for (int ft = 0; ft < 4; ++ft)
      acc[mt][ft] = (floatx4){0.f, 0.f, 0.f, 0.f};

  // B staging: dest = wave-uniform base + lane*16B (linear); swizzle on global source.
#define STAGE_B(KT)                                                                  \
  {                                                                                  \
    _Pragma("unroll")                                                                \
    for (int pass = 0; pass < 8; ++pass) {                                           \
      const int row = pass * 32 + (tid >> 4);                                        \
      const int kc  = tid & 15;                                                      \
      const unsigned short* gp =                                                     \
          Wt + (size_t)row * KD + (KT) * 128 + ((kc ^ (row & 15)) << 3);             \
      unsigned short* l = (unsigned short*)&smB[row * 128 + kc * 8];                 \
      __builtin_amdgcn_global_load_lds(                                              \
          (const __attribute__((address_space(1))) unsigned int*)gp,                 \
          (__attribute__((address_space(3))) unsigned int*)l, 16, 0, 0);             \
    }                                                                                \
  }

  // ---- prologue: B tile 0 DMA + tap 0 interp
  STAGE_B(0)
  interp_tap(xb, offp, i, p, c0, 0, smA);
  __syncthreads();

  for (int kt = 0; kt < 9; ++kt) {
    // ---- MFMA phase: wave's K-half of this tap
#pragma unroll
    for (int ks = 0; ks < 2; ++ks) {
      bf16x8 afr[4], bfr[4];
      const int slot = (((kg * 8 + ks * 4 + aq) ^ arow) << 3);
#pragma unroll
      for (int mt = 0; mt < 4; ++mt)
        afr[mt] = *(const bf16x8*)&smA[(mt * 16 + arow) * 128 + slot];
#pragma unroll
      for (int ft = 0; ft < 4; ++ft)
        bfr[ft] = *(const bf16x8*)&smB[(fg * 64 + ft * 16 + arow) * 128 + slot];
#pragma unroll
      for (int mt = 0; mt < 4; ++mt)
#pragma unroll
        for (int ft = 0; ft < 4; ++ft)
          acc[mt][ft] = __builtin_amdgcn_mfma_f32_16x16x32_bf16(
              afr[mt], bfr[ft], acc[mt][ft], 0, 0, 0);
    }
    __syncthreads();   // all reads done -> buffers free for overwrite

    if (kt < 8) {
      STAGE_B(kt + 1)                              // B-DMA issues first (in-order vmcnt)
      interp_tap(xb, offp, i, p, c0, kt + 1, smA); // gathers+lerp hide DMA latency
      __syncthreads();  // drains vmcnt (B-DMA) + lgkm (smA writes)
    }
  }
#undef STAGE_B

  // ---- epilogue: combine K-halves via swizzled LDS exchange (reuse smB)
  float* ex = (float*)smB;
  if (kg == 1) {
#pragma unroll
    for (int mt = 0; mt < 4; ++mt)
#pragma unroll
      for (int ft = 0; ft < 4; ++ft) {
        const int f  = fg * 64 + ft * 16 + arow;
        const int cm = mt * 4 + aq;
        *(floatx4*)&ex[f * 64 + ((cm ^ arow) << 2)] = acc[mt][ft];
      }
  }
  __syncthreads();
  if (kg == 0) {
    float bv[4];
#pragma unroll
    for (int ft = 0; ft < 4; ++ft)
      bv[ft] = bias[fg * 64 + ft * 16 + arow];
#pragma unroll
    for (int mt = 0; mt < 4; ++mt) {
#pragma unroll
      for (int ft = 0; ft < 4; ++ft) {
        const int f  = fg * 64 + ft * 16 + arow;
        const int cm = mt * 4 + aq;
        floatx4 o = *(const floatx4*)&ex[f * 64 + ((cm ^ arow) << 2)];
#pragma unroll
        for (int r = 0; r < 4; ++r) {
          const int m = m0 + mt * 16 + aq * 4 + r;
          // non-temporal: keep the 33.5 MB output stream from evicting Xb/Wt in L2
          __builtin_nontemporal_store(acc[mt][ft][r] + o[r] + bv[ft],
                                      &Out[(size_t)m * FF + f]);
        }
      }
    }
  }
}

extern "C" void kernel_launch(void* const* d_in, const int* in_sizes, int n_in,
                              void* d_out, int out_size, void* d_ws, size_t ws_size,
                              hipStream_t stream) {
  const float* X    = (const float*)d_in[0];
  const float* Off  = (const float*)d_in[1];
  const float* W    = (const float*)d_in[2];
  const float* bias = (const float*)d_in[3];
  float* Out = (float*)d_out;

  unsigned short* Wt = (unsigned short*)d_ws;                  // 294912 shorts
  unsigned short* Xb = Wt + (size_t)FF * KD;                   // 4194304 shorts

  prep_kernel<<<XCVT_BLOCKS + WT_BLOCKS, 256, 0, stream>>>(X, W, Xb, Wt);
  fused_kernel<<<512, 512, 0, stream>>>(Xb, Off, Wt, bias, Out);
}